// Round 1
// baseline (1101.035 us; speedup 1.0000x reference)
//
#include <hip/hip_runtime.h>

// NeuralInelasticModel: fused forward + Jacobian.
// NT*NB = 65536 samples, NS=6, NI=8, H=256, all fp32.
// out = [ydot(65536*6) | dydot_dy(65536*36) | dydot_de(65536*6) | dydot_dT(65536*6)]

#define NSAMP (64 * 1024)
#define NS_ 6
#define NI_ 8
#define H_ 256
#define SB 8
#define NGROUPS (NSAMP / SB)

#define OFF_YDOT 0
#define OFF_DY (NSAMP * 6)
#define OFF_DE (OFF_DY + NSAMP * 36)
#define OFF_DT (OFF_DE + NSAMP * 6)

__global__ __launch_bounds__(256, 2) void fused_kernel(
    const float* __restrict__ y,      // [NSAMP][6]
    const float* __restrict__ erate,  // [NSAMP]
    const float* __restrict__ Tin,    // [NSAMP]
    const float* __restrict__ w1,     // [256][8]
    const float* __restrict__ w2,     // [256][256]
    const float* __restrict__ w3,     // [6][256]
    const float* __restrict__ b1,     // [256]
    const float* __restrict__ b2,     // [256]
    const float* __restrict__ b3,     // [6]
    float* __restrict__ out)
{
    __shared__ __align__(16) float xs[SB][NI_];     // per-group inputs
    __shared__ __align__(16) float v1s[H_][SB];     // relu(z1), [j][s]
    __shared__ __align__(16) float v2s[H_][SB];     // relu(z2), [h][s]
    __shared__ __align__(16) float w1s[H_][NI_];    // w1 rows
    __shared__ __align__(16) float w3t[H_][NI_];    // w3 transposed, cols 6,7 = 0
    __shared__ __align__(16) float Bsh[NS_][H_];    // one sample's masked B
    __shared__ __align__(16) float Jpart[64][4];
    __shared__ float b3s[NS_];

    const int tid = threadIdx.x;

    // ---- block init: stage weights ----
    float w1r[NI_];
#pragma unroll
    for (int k = 0; k < NI_; ++k) {
        float v = w1[tid * NI_ + k];
        w1r[k] = v;
        w1s[tid][k] = v;
    }
#pragma unroll
    for (int i = 0; i < NI_; ++i)
        w3t[tid][i] = (i < NS_) ? w3[i * H_ + tid] : 0.0f;
    const float b1r = b1[tid];
    const float b2r = b2[tid];
    if (tid < NS_) b3s[tid] = b3[tid];
    __syncthreads();

    const float* w2row = w2 + tid * H_;  // row tid (z2 phase)
    const float* w2col = w2 + tid;       // column tid (B phase)

    for (int g = blockIdx.x; g < NGROUPS; g += gridDim.x) {
        const int s0 = g * SB;

        // ---- phase A: load x for 8 samples ----
        if (tid < SB * NI_) {
            int s = tid >> 3, k = tid & 7;
            float v;
            if (k < NS_)      v = y[(s0 + s) * NS_ + k];
            else if (k == NS_) v = erate[s0 + s];
            else               v = Tin[s0 + s];
            xs[s][k] = v;
        }
        __syncthreads();

        // ---- z1 / v1: thread tid = hidden unit ----
        float v1r[SB];
#pragma unroll
        for (int s = 0; s < SB; ++s) {
            float z = b1r;
#pragma unroll
            for (int k = 0; k < NI_; ++k) z = fmaf(w1r[k], xs[s][k], z);
            float v = fmaxf(z, 0.0f);
            v1r[s] = v;        // m1 for column tid later: v1r[s] > 0
            v1s[tid][s] = v;
        }
        __syncthreads();

        // ---- phase B: z2 = w2 @ v1 (+b2), v2 = relu ----
        float acc[SB];
#pragma unroll
        for (int s = 0; s < SB; ++s) acc[s] = b2r;
        for (int j = 0; j < H_; j += 4) {
            float4 wv = *(const float4*)(w2row + j);
            float wj[4] = {wv.x, wv.y, wv.z, wv.w};
#pragma unroll
            for (int u = 0; u < 4; ++u) {
                float4 a = *(const float4*)&v1s[j + u][0];  // LDS broadcast
                float4 b = *(const float4*)&v1s[j + u][4];
                acc[0] = fmaf(wj[u], a.x, acc[0]);
                acc[1] = fmaf(wj[u], a.y, acc[1]);
                acc[2] = fmaf(wj[u], a.z, acc[2]);
                acc[3] = fmaf(wj[u], a.w, acc[3]);
                acc[4] = fmaf(wj[u], b.x, acc[4]);
                acc[5] = fmaf(wj[u], b.y, acc[5]);
                acc[6] = fmaf(wj[u], b.z, acc[6]);
                acc[7] = fmaf(wj[u], b.w, acc[7]);
            }
        }
#pragma unroll
        for (int s = 0; s < SB; ++s)
            v2s[tid][s] = fmaxf(acc[s], 0.0f);  // m2 == (v2 > 0)
        __syncthreads();

        // ---- phase C: B[s][i][tid] = sum_h w3[i][h]*m2[s][h]*w2[h][tid] ----
        float Bacc[SB * NS_];
#pragma unroll
        for (int q = 0; q < SB * NS_; ++q) Bacc[q] = 0.0f;
#pragma unroll 2
        for (int h = 0; h < H_; ++h) {
            float wj = w2col[h * H_];                    // coalesced global
            float4 a0 = *(const float4*)&w3t[h][0];      // LDS broadcast
            float4 a1 = *(const float4*)&w3t[h][4];
            float4 m0 = *(const float4*)&v2s[h][0];
            float4 m1v = *(const float4*)&v2s[h][4];
            float w3h[NS_] = {a0.x, a0.y, a0.z, a0.w, a1.x, a1.y};
            float ts[SB];
            ts[0] = (m0.x > 0.0f) ? wj : 0.0f;
            ts[1] = (m0.y > 0.0f) ? wj : 0.0f;
            ts[2] = (m0.z > 0.0f) ? wj : 0.0f;
            ts[3] = (m0.w > 0.0f) ? wj : 0.0f;
            ts[4] = (m1v.x > 0.0f) ? wj : 0.0f;
            ts[5] = (m1v.y > 0.0f) ? wj : 0.0f;
            ts[6] = (m1v.z > 0.0f) ? wj : 0.0f;
            ts[7] = (m1v.w > 0.0f) ? wj : 0.0f;
#pragma unroll
            for (int s = 0; s < SB; ++s)
#pragma unroll
                for (int i = 0; i < NS_; ++i)
                    Bacc[s * NS_ + i] = fmaf(ts[s], w3h[i], Bacc[s * NS_ + i]);
        }

        // ---- phase D: per sample, J = (B .* m1) @ w1, plus ydot ----
#pragma unroll 1
        for (int s = 0; s < SB; ++s) {
            const float m1f = (v1r[s] > 0.0f) ? 1.0f : 0.0f;
#pragma unroll
            for (int i = 0; i < NS_; ++i)
                Bsh[i][tid] = Bacc[s * NS_ + i] * m1f;
            __syncthreads();

            const int e = tid & 63, c = tid >> 6;
            float part = 0.0f;
            if (e < 48) {
                const int ie = e >> 3, le = e & 7;
                for (int j = 0; j < 64; ++j)
                    part = fmaf(Bsh[ie][c * 64 + j], w1s[c * 64 + j][le], part);
            } else if (e < 54) {
                const int ie = e - 48;
                for (int hh = 0; hh < 64; ++hh)
                    part = fmaf(w3t[c * 64 + hh][ie], v2s[c * 64 + hh][s], part);
            }
            Jpart[e][c] = part;
            __syncthreads();

            if (tid < 64) {
                const int ee = tid;
                float v = Jpart[ee][0] + Jpart[ee][1] + Jpart[ee][2] + Jpart[ee][3];
                const long sg = (long)(s0 + s);
                if (ee < 48) {
                    const int ie = ee >> 3, le = ee & 7;
                    if (le < NS_)
                        out[OFF_DY + sg * 36 + ie * 6 + le] = v;
                    else if (le == 6)
                        out[OFF_DE + sg * 6 + ie] = v;
                    else
                        out[OFF_DT + sg * 6 + ie] = v;
                } else if (ee < 54) {
                    const int ie = ee - 48;
                    out[OFF_YDOT + sg * 6 + ie] = v + b3s[ie];
                }
            }
        }
    }
}

extern "C" void kernel_launch(void* const* d_in, const int* in_sizes, int n_in,
                              void* d_out, int out_size, void* d_ws, size_t ws_size,
                              hipStream_t stream) {
    // setup_inputs order: t(unused), y, erate, T, w1, w2, w3, b1, b2, b3
    const float* y     = (const float*)d_in[1];
    const float* erate = (const float*)d_in[2];
    const float* Tin   = (const float*)d_in[3];
    const float* w1    = (const float*)d_in[4];
    const float* w2    = (const float*)d_in[5];
    const float* w3    = (const float*)d_in[6];
    const float* b1    = (const float*)d_in[7];
    const float* b2    = (const float*)d_in[8];
    const float* b3    = (const float*)d_in[9];
    float* out = (float*)d_out;

    fused_kernel<<<dim3(2048), dim3(256), 0, stream>>>(
        y, erate, Tin, w1, w2, w3, b1, b2, b3, out);
}

// Round 3
// 657.247 us; speedup vs baseline: 1.6752x; 1.6752x over previous
//
#include <hip/hip_runtime.h>
#include <hip/hip_bf16.h>

// NeuralInelasticModel fused fwd + Jacobian, MFMA bf16 version.
// 65536 samples, NS=6, NI=8, H=256.
// out = [ydot(65536*6) | dy(65536*36) | de(65536*6) | dT(65536*6)]
// z2 (whose SIGN feeds the m2 mask) is computed via 3-term bf16 split
// (hi+mid+lo = 24 mantissa bits) with 6 MFMA products -> fp32-chain accuracy.

typedef unsigned short ushort_t;
typedef __attribute__((ext_vector_type(8))) short bf16x8;   // 8 bf16 = 4 VGPRs
typedef __attribute__((ext_vector_type(4))) float f32x4;

#define NSAMP (64 * 1024)
#define NGROUPS (NSAMP / 8)
#define OFF_YDOT 0
#define OFF_DY (NSAMP * 6)
#define OFF_DE (OFF_DY + NSAMP * 36)
#define OFF_DT (OFF_DE + NSAMP * 6)

// Weights repacked into MFMA B-fragment order:
// frag elem idx = ((nt*8 + kt)*64 + lane)*8 + jj,
// value = B[k = kt*32 + (lane>>4)*8 + jj][n = nt*16 + (lane&15)]
__device__ __align__(16) ushort_t g_w2T_hi[65536];   // z2 GEMM: B[k=j][n=h] = w2[h][j]
__device__ __align__(16) ushort_t g_w2T_mid[65536];
__device__ __align__(16) ushort_t g_w2T_lo[65536];
__device__ __align__(16) ushort_t g_w2B[65536];      // B GEMM:  B[k=h][n=j] = w2[h][j]
__device__ __align__(16) ushort_t g_w1e[4096];       // J GEMM:  B[k=j][n=kout] = w1[j][kout] (kout<8 else 0)

static __device__ __forceinline__ ushort_t f2bf(float f) {
    union { __hip_bfloat16 b; ushort_t u; } c;
    c.b = __float2bfloat16(f);
    return c.u;
}
static __device__ __forceinline__ float bf2f(ushort_t u) {
    union { ushort_t u; __hip_bfloat16 b; } c;
    c.u = u;
    return __bfloat162float(c.b);
}

__global__ void prep_kernel(const float* __restrict__ w1, const float* __restrict__ w2) {
    const int gtid = blockIdx.x * blockDim.x + threadIdx.x;
    const int stride = gridDim.x * blockDim.x;
    for (int idx = gtid; idx < 65536; idx += stride) {
        const int nt = idx >> 12, kt = (idx >> 9) & 7, L = (idx >> 3) & 63, jj = idx & 7;
        const int n = nt * 16 + (L & 15);
        const int k = kt * 32 + ((L >> 4) & 3) * 8 + jj;
        // w2T: B[k=j][n=h] = w2[h*256 + j]  (h=n, j=k), 3-way bf16 split
        const float vT = w2[n * 256 + k];
        const ushort_t hi = f2bf(vT);
        const float r1 = vT - bf2f(hi);
        const ushort_t mid = f2bf(r1);
        const float r2 = r1 - bf2f(mid);
        g_w2T_hi[idx]  = hi;
        g_w2T_mid[idx] = mid;
        g_w2T_lo[idx]  = f2bf(r2);
        // w2B: B[k=h][n=j] = w2[h*256 + j]  (h=k, j=n)
        g_w2B[idx] = f2bf(w2[k * 256 + n]);
    }
    for (int idx = gtid; idx < 4096; idx += stride) {
        const int kt = idx >> 9, L = (idx >> 3) & 63, jj = idx & 7;
        const int kout = L & 15;
        const int j = kt * 32 + ((L >> 4) & 3) * 8 + jj;
        g_w1e[idx] = (kout < 8) ? f2bf(w1[j * 8 + kout]) : (ushort_t)0;
    }
}

// LDS layout (bytes). v1 arrays are [8 s][264 j] (A-frag rows 8..15 duplicate
// rows 0..7 via (l15&7) -- their C rows are discarded).
//   0      v1hi  (4224)
//   4224   v1mid (4224)  -- ALIASED after phase B: Jsh[48][8] f32 (1536) @4224, ydsh[48] f32 @5760
//   8448   v1lo  (4224)
//   12672  v2B: B-frag [8 kt][64 lane][8 jj] bf16 (8192); doubles as m2 mask (u16 != 0)
//   20864  A2:  A-frag [3 mt][8 kt][64 lane][8 jj] bf16 (24576); reused for Bm in phase D
//   45440  w3bf [6][264] bf16 (3168)
//   48608  xs [8][8] f32 (256)
//   48864  b3s [6] f32 (24)
#define SMEM_BYTES 48896

__global__ __launch_bounds__(256, 3) void fused_kernel(
    const float* __restrict__ y, const float* __restrict__ erate,
    const float* __restrict__ Tin, const float* __restrict__ w1,
    const float* __restrict__ w3, const float* __restrict__ b1,
    const float* __restrict__ b2, const float* __restrict__ b3,
    float* __restrict__ out)
{
    __shared__ __align__(16) char smem[SMEM_BYTES];
    ushort_t* v1hi  = (ushort_t*)(smem + 0);
    ushort_t* v1mid = (ushort_t*)(smem + 4224);
    ushort_t* v1lo  = (ushort_t*)(smem + 8448);
    float*    Jsh   = (float*)(smem + 4224);   // alias of v1mid (dead after phase B)
    float*    ydsh  = (float*)(smem + 5760);
    ushort_t* v2B   = (ushort_t*)(smem + 12672);
    ushort_t* A2    = (ushort_t*)(smem + 20864);
    ushort_t* w3bf  = (ushort_t*)(smem + 45440);
    float*    xs    = (float*)(smem + 48608);
    float*    b3s   = (float*)(smem + 48864);

    const int tid  = threadIdx.x;
    const int lane = tid & 63;
    const int wave = tid >> 6;
    const int l15  = lane & 15;
    const int quad = lane >> 4;

    // ---- per-block init ----
    float w1r[8];
#pragma unroll
    for (int k = 0; k < 8; ++k) w1r[k] = w1[tid * 8 + k];
    const float b1r = b1[tid];
    float b2v[4];
#pragma unroll
    for (int n = 0; n < 4; ++n) b2v[n] = b2[(wave * 4 + n) * 16 + l15];
#pragma unroll
    for (int i = 0; i < 6; ++i) w3bf[i * 264 + tid] = f2bf(w3[i * 256 + tid]);
    if (tid < 6) b3s[tid] = b3[tid];

    for (int g = blockIdx.x; g < NGROUPS; g += gridDim.x) {
        const int s0 = g * 8;

        // ---- stage x ----
        if (tid < 64) {
            const int s = tid >> 3, k = tid & 7;
            float v;
            if (k < 6)       v = y[(s0 + s) * 6 + k];
            else if (k == 6) v = erate[s0 + s];
            else             v = Tin[s0 + s];
            xs[s * 8 + k] = v;
        }
        __syncthreads();  // also guards prev-group Jsh reads vs v1mid writes below

        // ---- z1 (exact fp32) + 3-way bf16 split of v1; thread = hidden unit j ----
#pragma unroll
        for (int s = 0; s < 8; ++s) {
            float z = b1r;
#pragma unroll
            for (int k = 0; k < 8; ++k) z = fmaf(w1r[k], xs[s * 8 + k], z);
            const float v = fmaxf(z, 0.0f);
            const ushort_t hi = f2bf(v);
            const float r1 = v - bf2f(hi);
            const ushort_t mid = f2bf(r1);
            const float r2 = r1 - bf2f(mid);
            v1hi[s * 264 + tid]  = hi;   // also the m1 mask (u16 != 0 <=> z1 > 0)
            v1mid[s * 264 + tid] = mid;
            v1lo[s * 264 + tid]  = f2bf(r2);
        }
        __syncthreads();

        // ---- phase B: z2 = v1^T @ w2^T, 3-way split (6 MFMAs), M=16(s) N=256(h) K=256(j) ----
        {
            f32x4 cz[4];
#pragma unroll
            for (int n = 0; n < 4; ++n) cz[n] = (f32x4){0, 0, 0, 0};
#pragma unroll 2
            for (int kt = 0; kt < 8; ++kt) {
                const int aoff = (l15 & 7) * 264 + kt * 32 + quad * 8;
                bf16x8 ahi = *(const bf16x8*)&v1hi[aoff];
                bf16x8 ami = *(const bf16x8*)&v1mid[aoff];
                bf16x8 alo = *(const bf16x8*)&v1lo[aoff];
#pragma unroll
                for (int n = 0; n < 4; ++n) {
                    const int bidx = (((wave * 4 + n) * 8 + kt) * 64 + lane) * 8;
                    bf16x8 bh = *(const bf16x8*)&g_w2T_hi[bidx];
                    bf16x8 bm = *(const bf16x8*)&g_w2T_mid[bidx];
                    bf16x8 bl = *(const bf16x8*)&g_w2T_lo[bidx];
                    cz[n] = __builtin_amdgcn_mfma_f32_16x16x32_bf16(alo, bh, cz[n], 0, 0, 0);
                    cz[n] = __builtin_amdgcn_mfma_f32_16x16x32_bf16(ami, bm, cz[n], 0, 0, 0);
                    cz[n] = __builtin_amdgcn_mfma_f32_16x16x32_bf16(ahi, bl, cz[n], 0, 0, 0);
                    cz[n] = __builtin_amdgcn_mfma_f32_16x16x32_bf16(ami, bh, cz[n], 0, 0, 0);
                    cz[n] = __builtin_amdgcn_mfma_f32_16x16x32_bf16(ahi, bm, cz[n], 0, 0, 0);
                    cz[n] = __builtin_amdgcn_mfma_f32_16x16x32_bf16(ahi, bh, cz[n], 0, 0, 0);
                }
            }
            // epilogue: v2 = relu(z2 + b2) -> v2B (B-frag layout, doubles as m2)
#pragma unroll
            for (int n = 0; n < 4; ++n) {
                const int h = (wave * 4 + n) * 16 + l15;
                const int ktd = h >> 5, qd = (h >> 3) & 3, jj = h & 7;
#pragma unroll
                for (int r = 0; r < 4; ++r) {
                    const int s = quad * 4 + r;  // C layout: row = quad*4 + reg
                    if (s < 8) {
                        const float v2 = fmaxf(cz[n][r] + b2v[n], 0.0f);
                        v2B[(ktd * 64 + (s | (qd << 4))) * 8 + jj] = f2bf(v2);
                    }
                }
            }
        }
        __syncthreads();

        // ---- build A2[m = s*6+i][h] = m2[s][h] ? w3[i][h] : 0 in A-frag layout ----
        if (tid < 192) {
            const int mt = tid >> 6;
            const int m = mt * 16 + l15;
            const int s = m / 6, i = m - s * 6;
#pragma unroll
            for (int kt = 0; kt < 8; ++kt) {
                bf16x8 vv = *(const bf16x8*)&v2B[(kt * 64 + (s | (quad << 4))) * 8];
                bf16x8 wv = *(const bf16x8*)&w3bf[i * 264 + kt * 32 + quad * 8];
                bf16x8 o;
#pragma unroll
                for (int e = 0; e < 8; ++e)
                    o[e] = ((ushort_t)vv[e] != 0) ? wv[e] : (short)0;
                *(bf16x8*)&A2[((mt * 8 + kt) * 64 + lane) * 8] = o;
            }
        }
        __syncthreads();

        // ---- phase C: B = A2 @ w2 (M=48 N=256 K=256), wave w owns nt = 4w..4w+3;
        //      wave 3 also does the ydot tile (B-operand = v2 from LDS) ----
        {
            f32x4 cc[3][4], cy[3];
#pragma unroll
            for (int mt = 0; mt < 3; ++mt) {
#pragma unroll
                for (int n = 0; n < 4; ++n) cc[mt][n] = (f32x4){0, 0, 0, 0};
                cy[mt] = (f32x4){0, 0, 0, 0};
            }
#pragma unroll 2
            for (int kt = 0; kt < 8; ++kt) {
                bf16x8 a[3];
#pragma unroll
                for (int mt = 0; mt < 3; ++mt)
                    a[mt] = *(const bf16x8*)&A2[((mt * 8 + kt) * 64 + lane) * 8];
#pragma unroll
                for (int n = 0; n < 4; ++n) {
                    bf16x8 b = *(const bf16x8*)&g_w2B[(((wave * 4 + n) * 8 + kt) * 64 + lane) * 8];
#pragma unroll
                    for (int mt = 0; mt < 3; ++mt)
                        cc[mt][n] = __builtin_amdgcn_mfma_f32_16x16x32_bf16(a[mt], b, cc[mt][n], 0, 0, 0);
                }
                if (wave == 3) {
                    bf16x8 bv = *(const bf16x8*)&v2B[(kt * 64 + lane) * 8];
#pragma unroll
                    for (int mt = 0; mt < 3; ++mt)
                        cy[mt] = __builtin_amdgcn_mfma_f32_16x16x32_bf16(a[mt], bv, cy[mt], 0, 0, 0);
                }
            }
            __syncthreads();  // all A2 reads complete before Bm overwrites

            // epilogue: Bm = (B .* m1) -> bf16, back into A2 in A-frag layout
#pragma unroll
            for (int mt = 0; mt < 3; ++mt) {
#pragma unroll
                for (int n = 0; n < 4; ++n) {
                    const int j = (wave * 4 + n) * 16 + l15;  // C layout: col = lane&15
                    const int ktd = j >> 5, qd = (j >> 3) & 3, jjd = j & 7;
#pragma unroll
                    for (int r = 0; r < 4; ++r) {
                        const int m = mt * 16 + quad * 4 + r;  // C layout: row = quad*4 + reg
                        const int s = m / 6;
                        const ushort_t bm =
                            (v1hi[s * 264 + j] != 0) ? f2bf(cc[mt][n][r]) : (ushort_t)0;
                        A2[((mt * 8 + ktd) * 64 + ((m & 15) | (qd << 4))) * 8 + jjd] = bm;
                    }
                }
            }
            if (wave == 3) {  // ydot from the extra tile's diagonal
#pragma unroll
                for (int mt = 0; mt < 3; ++mt) {
#pragma unroll
                    for (int r = 0; r < 4; ++r) {
                        const int m = mt * 16 + quad * 4 + r;
                        const int s = m / 6, i = m - s * 6;
                        if (l15 == s) ydsh[m] = cy[mt][r] + b3s[i];
                    }
                }
            }
        }
        __syncthreads();

        // ---- phase D: J = Bm @ w1e (M=48 N=16 K=256); wave w = M-tile w ----
        if (wave < 3) {
            const int mt = wave;
            f32x4 dc = {0, 0, 0, 0};
#pragma unroll
            for (int kt = 0; kt < 8; ++kt) {
                bf16x8 a = *(const bf16x8*)&A2[((mt * 8 + kt) * 64 + lane) * 8];
                bf16x8 b = *(const bf16x8*)&g_w1e[(kt * 64 + lane) * 8];
                dc = __builtin_amdgcn_mfma_f32_16x16x32_bf16(a, b, dc, 0, 0, 0);
            }
            if (l15 < 8) {
#pragma unroll
                for (int r = 0; r < 4; ++r) {
                    const int m = mt * 16 + quad * 4 + r;
                    Jsh[m * 8 + l15] = dc[r];
                }
            }
        }
        __syncthreads();

        // ---- coalesced output staging ----
        {
            const long base6 = (long)s0 * 6;
            {
                const int u = tid;  // dy dwords 0..255
                const int s = u / 36, rem = u - s * 36, ii = rem / 6, jy = rem - ii * 6;
                out[OFF_DY + (long)s0 * 36 + u] = Jsh[(s * 6 + ii) * 8 + jy];
            }
            if (tid < 32) {  // dy dwords 256..287
                const int u = 256 + tid;
                const int s = u / 36, rem = u - s * 36, ii = rem / 6, jy = rem - ii * 6;
                out[OFF_DY + (long)s0 * 36 + u] = Jsh[(s * 6 + ii) * 8 + jy];
            }
            if (tid < 48) out[OFF_YDOT + base6 + tid] = ydsh[tid];
            const int t2 = tid - 64;
            if (t2 >= 0 && t2 < 48) out[OFF_DE + base6 + t2] = Jsh[t2 * 8 + 6];
            const int t3 = tid - 128;
            if (t3 >= 0 && t3 < 48) out[OFF_DT + base6 + t3] = Jsh[t3 * 8 + 7];
        }
    }
}

extern "C" void kernel_launch(void* const* d_in, const int* in_sizes, int n_in,
                              void* d_out, int out_size, void* d_ws, size_t ws_size,
                              hipStream_t stream) {
    // setup_inputs order: t(0,unused), y(1), erate(2), T(3), w1(4), w2(5), w3(6), b1(7), b2(8), b3(9)
    const float* y     = (const float*)d_in[1];
    const float* erate = (const float*)d_in[2];
    const float* Tin   = (const float*)d_in[3];
    const float* w1    = (const float*)d_in[4];
    const float* w2    = (const float*)d_in[5];
    const float* w3    = (const float*)d_in[6];
    const float* b1    = (const float*)d_in[7];
    const float* b2    = (const float*)d_in[8];
    const float* b3    = (const float*)d_in[9];
    float* out = (float*)d_out;

    prep_kernel<<<dim3(64), dim3(256), 0, stream>>>(w1, w2);
    fused_kernel<<<dim3(NGROUPS), dim3(256), 0, stream>>>(
        y, erate, Tin, w1, w3, b1, b2, b3, out);
}

// Round 4
// 511.116 us; speedup vs baseline: 2.1542x; 1.2859x over previous
//
#include <hip/hip_runtime.h>
#include <hip/hip_bf16.h>

// NeuralInelasticModel fused fwd + Jacobian, MFMA bf16, SB=16 samples/block.
// 65536 samples, NS=6, NI=8, H=256.
// out = [ydot(65536*6) | dy(65536*36) | de(65536*6) | dT(65536*6)]
// z2 (sign feeds m2 mask) via 3-term bf16 split (6 MFMA products) -> fp32-chain accuracy.

typedef unsigned short ushort_t;
typedef __attribute__((ext_vector_type(8))) short bf16x8;   // 8 bf16 = 4 VGPRs
typedef __attribute__((ext_vector_type(4))) float f32x4;

#define NSAMP (64 * 1024)
#define NG16 (NSAMP / 16)
#define OFF_YDOT 0
#define OFF_DY (NSAMP * 6)
#define OFF_DE (OFF_DY + NSAMP * 36)
#define OFF_DT (OFF_DE + NSAMP * 6)

// Weights repacked into MFMA B-fragment order:
// frag elem idx = ((nt*8 + kt)*64 + lane)*8 + jj,
// value = B[k = kt*32 + (lane>>4)*8 + jj][n = nt*16 + (lane&15)]
__device__ __align__(16) ushort_t g_w2T_hi[65536];   // z2 GEMM: B[k=j][n=h] = w2[h][j]
__device__ __align__(16) ushort_t g_w2T_mid[65536];
__device__ __align__(16) ushort_t g_w2T_lo[65536];
__device__ __align__(16) ushort_t g_w2B[65536];      // B GEMM:  B[k=h][n=j] = w2[h][j]
__device__ __align__(16) ushort_t g_w1e[4096];       // J GEMM:  B[k=j][n=kout] = w1[j][kout] (kout<8 else 0)
__device__ __align__(16) ushort_t g_w3b[1536];       // w3 bf16 row-major [6][256]

static __device__ __forceinline__ ushort_t f2bf(float f) {
    union { __hip_bfloat16 b; ushort_t u; } c;
    c.b = __float2bfloat16(f);
    return c.u;
}
static __device__ __forceinline__ float bf2f(ushort_t u) {
    union { ushort_t u; __hip_bfloat16 b; } c;
    c.u = u;
    return __bfloat162float(c.b);
}

__global__ void prep_kernel(const float* __restrict__ w1, const float* __restrict__ w2,
                            const float* __restrict__ w3) {
    const int gtid = blockIdx.x * blockDim.x + threadIdx.x;
    const int stride = gridDim.x * blockDim.x;
    for (int idx = gtid; idx < 65536; idx += stride) {
        const int nt = idx >> 12, kt = (idx >> 9) & 7, L = (idx >> 3) & 63, jj = idx & 7;
        const int n = nt * 16 + (L & 15);
        const int k = kt * 32 + ((L >> 4) & 3) * 8 + jj;
        const float vT = w2[n * 256 + k];          // w2T: B[k=j][n=h]
        const ushort_t hi = f2bf(vT);
        const float r1 = vT - bf2f(hi);
        const ushort_t mid = f2bf(r1);
        g_w2T_hi[idx]  = hi;
        g_w2T_mid[idx] = mid;
        g_w2T_lo[idx]  = f2bf(r1 - bf2f(mid));
        g_w2B[idx] = f2bf(w2[k * 256 + n]);        // w2B: B[k=h][n=j]
    }
    for (int idx = gtid; idx < 4096; idx += stride) {
        const int kt = idx >> 9, L = (idx >> 3) & 63, jj = idx & 7;
        const int kout = L & 15;
        const int j = kt * 32 + ((L >> 4) & 3) * 8 + jj;
        g_w1e[idx] = (kout < 8) ? f2bf(w1[j * 8 + kout]) : (ushort_t)0;
    }
    for (int idx = gtid; idx < 1536; idx += stride) g_w3b[idx] = f2bf(w3[idx]);
}

// LDS layout (40960 B total -> 4 blocks/CU):
//   0      v1hi: A-frag [8 kt][64 lane][8 jj] bf16 (8192). Persists (m1 mask source).
//   8192   A2:   A-frag [3 mt][8 kt][64][8] bf16 (24576). Aliases:
//            v1mid @8192 (8192), v1lo @16384 (8192)  -- dead after phase B
//            xs [16][8] f32 @24576 (512)             -- dead after z1
//            Jsh [48][8] f32 @8192 (1536), ydsh[48] f32 @9728 (192)
//                -- written only AFTER phase D per chunk (A2 dead), rebuilt next chunk
//   32768  v2B: B-frag [8 kt][64][8] bf16 (8192); n-dim = sample 0..15; doubles as m2 mask.
#define SMEM_BYTES 40960

__global__ __launch_bounds__(256, 4) void fused_kernel(
    const float* __restrict__ y, const float* __restrict__ erate,
    const float* __restrict__ Tin, const float* __restrict__ w1,
    const float* __restrict__ b1, const float* __restrict__ b2,
    const float* __restrict__ b3, float* __restrict__ out)
{
    __shared__ __align__(16) char smem[SMEM_BYTES];
    ushort_t* v1hi  = (ushort_t*)(smem + 0);
    ushort_t* v1mid = (ushort_t*)(smem + 8192);
    ushort_t* v1lo  = (ushort_t*)(smem + 16384);
    ushort_t* A2    = (ushort_t*)(smem + 8192);
    float*    xs    = (float*)(smem + 24576);
    float*    Jsh   = (float*)(smem + 8192);
    float*    ydsh  = (float*)(smem + 9728);
    ushort_t* v2B   = (ushort_t*)(smem + 32768);

    const int tid  = threadIdx.x;
    const int lane = tid & 63;
    const int wave = tid >> 6;
    const int l15  = lane & 15;
    const int quad = lane >> 4;

    // per-thread weight regs for z1 (thread = hidden unit j)
    float w1r[8];
#pragma unroll
    for (int k = 0; k < 8; ++k) w1r[k] = w1[tid * 8 + k];
    const float b1r = b1[tid];
    float b2v[4];
#pragma unroll
    for (int n = 0; n < 4; ++n) b2v[n] = b2[(wave * 4 + n) * 16 + l15];

    for (int g = blockIdx.x; g < NG16; g += gridDim.x) {
        const int s0 = g * 16;

        // ---- stage x for 16 samples ----
        if (tid < 128) {
            const int s = tid >> 3, k = tid & 7;
            float v;
            if (k < 6)       v = y[(s0 + s) * 6 + k];
            else if (k == 6) v = erate[s0 + s];
            else             v = Tin[s0 + s];
            xs[s * 8 + k] = v;
        }
        __syncthreads();

        // ---- z1 (exact fp32) + 3-way bf16 split of v1, stored in A-frag layout ----
        {
            const int ktw = tid >> 5, qd = (tid >> 3) & 3, jj = tid & 7;
#pragma unroll
            for (int s = 0; s < 16; ++s) {
                float z = b1r;
#pragma unroll
                for (int k = 0; k < 8; ++k) z = fmaf(w1r[k], xs[s * 8 + k], z);
                const float v = fmaxf(z, 0.0f);
                const ushort_t hi = f2bf(v);
                const float r1 = v - bf2f(hi);
                const ushort_t mid = f2bf(r1);
                const int e = ((ktw * 64 + (s | (qd << 4))) * 8 + jj);
                v1hi[e]  = hi;   // also the m1 mask (u16 != 0 <=> z1 > 0)
                v1mid[e] = mid;
                v1lo[e]  = f2bf(r1 - bf2f(mid));
            }
        }
        __syncthreads();

        // ---- phase B: z2 = v1 @ w2^T, 3-way split (6 MFMAs), M=16(s) N=256(h) K=256(j) ----
        {
            f32x4 cz[4];
#pragma unroll
            for (int n = 0; n < 4; ++n) cz[n] = (f32x4){0, 0, 0, 0};
#pragma unroll 2
            for (int kt = 0; kt < 8; ++kt) {
                const int aoff = (kt * 64 + lane) * 8;
                bf16x8 ahi = *(const bf16x8*)&v1hi[aoff];
                bf16x8 ami = *(const bf16x8*)&v1mid[aoff];
                bf16x8 alo = *(const bf16x8*)&v1lo[aoff];
#pragma unroll
                for (int n = 0; n < 4; ++n) {
                    const int bidx = (((wave * 4 + n) * 8 + kt) * 64 + lane) * 8;
                    bf16x8 bh = *(const bf16x8*)&g_w2T_hi[bidx];
                    bf16x8 bm = *(const bf16x8*)&g_w2T_mid[bidx];
                    bf16x8 bl = *(const bf16x8*)&g_w2T_lo[bidx];
                    cz[n] = __builtin_amdgcn_mfma_f32_16x16x32_bf16(alo, bh, cz[n], 0, 0, 0);
                    cz[n] = __builtin_amdgcn_mfma_f32_16x16x32_bf16(ami, bm, cz[n], 0, 0, 0);
                    cz[n] = __builtin_amdgcn_mfma_f32_16x16x32_bf16(ahi, bl, cz[n], 0, 0, 0);
                    cz[n] = __builtin_amdgcn_mfma_f32_16x16x32_bf16(ami, bh, cz[n], 0, 0, 0);
                    cz[n] = __builtin_amdgcn_mfma_f32_16x16x32_bf16(ahi, bm, cz[n], 0, 0, 0);
                    cz[n] = __builtin_amdgcn_mfma_f32_16x16x32_bf16(ahi, bh, cz[n], 0, 0, 0);
                }
            }
            // epilogue: v2 = relu(z2 + b2) -> v2B (B-frag layout, n=sample; doubles as m2)
#pragma unroll
            for (int n = 0; n < 4; ++n) {
                const int h = (wave * 4 + n) * 16 + l15;
                const int ktd = h >> 5, qd = (h >> 3) & 3, jj = h & 7;
#pragma unroll
                for (int r = 0; r < 4; ++r) {
                    const int s = quad * 4 + r;  // C layout: row = quad*4 + reg
                    const float v2 = fmaxf(cz[n][r] + b2v[n], 0.0f);
                    v2B[(ktd * 64 + (s | (qd << 4))) * 8 + jj] = f2bf(v2);
                }
            }
        }

        // ---- chunks of 8 samples: phases C (B=A2@w2), D (J=Bm@w1e), epilogue ----
#pragma unroll 1
        for (int c = 0; c < 2; ++c) {
            __syncthreads();  // v2B ready (c=0) / prev chunk's Jsh reads done (c=1)

            // build A2[m = sl*6+i][h] = m2[sg][h] ? w3[i][h] : 0, A-frag layout
            if (tid < 192) {
                const int mt = tid >> 6;
                const int m = mt * 16 + l15;
                const int sl = m / 6, i = m - sl * 6;
                const int sg = c * 8 + sl;
#pragma unroll
                for (int kt = 0; kt < 8; ++kt) {
                    bf16x8 vv = *(const bf16x8*)&v2B[(kt * 64 + (sg | (quad << 4))) * 8];
                    bf16x8 wv = *(const bf16x8*)&g_w3b[i * 256 + kt * 32 + quad * 8];
                    bf16x8 o;
#pragma unroll
                    for (int e = 0; e < 8; ++e)
                        o[e] = ((ushort_t)vv[e] != 0) ? wv[e] : (short)0;
                    *(bf16x8*)&A2[((mt * 8 + kt) * 64 + lane) * 8] = o;
                }
            }
            __syncthreads();

            // phase C: B = A2 @ w2 (M=48 N=256 K=256); wave 3 also does ydot tile
            f32x4 cc[3][4], cy[3];
#pragma unroll
            for (int mt = 0; mt < 3; ++mt) {
#pragma unroll
                for (int n = 0; n < 4; ++n) cc[mt][n] = (f32x4){0, 0, 0, 0};
                cy[mt] = (f32x4){0, 0, 0, 0};
            }
#pragma unroll 2
            for (int kt = 0; kt < 8; ++kt) {
                bf16x8 a[3];
#pragma unroll
                for (int mt = 0; mt < 3; ++mt)
                    a[mt] = *(const bf16x8*)&A2[((mt * 8 + kt) * 64 + lane) * 8];
#pragma unroll
                for (int n = 0; n < 4; ++n) {
                    bf16x8 b = *(const bf16x8*)&g_w2B[(((wave * 4 + n) * 8 + kt) * 64 + lane) * 8];
#pragma unroll
                    for (int mt = 0; mt < 3; ++mt)
                        cc[mt][n] = __builtin_amdgcn_mfma_f32_16x16x32_bf16(a[mt], b, cc[mt][n], 0, 0, 0);
                }
                if (wave == 3) {
                    bf16x8 bv = *(const bf16x8*)&v2B[(kt * 64 + lane) * 8];
#pragma unroll
                    for (int mt = 0; mt < 3; ++mt)
                        cy[mt] = __builtin_amdgcn_mfma_f32_16x16x32_bf16(a[mt], bv, cy[mt], 0, 0, 0);
                }
            }
            __syncthreads();  // all A2 reads complete before Bm overwrites

            // epilogue: Bm = (B .* m1) -> bf16, back into A2 (A-frag layout)
#pragma unroll
            for (int mt = 0; mt < 3; ++mt) {
#pragma unroll
                for (int n = 0; n < 4; ++n) {
                    const int j = (wave * 4 + n) * 16 + l15;  // C layout: col = lane&15
                    const int ktd = j >> 5, qd = (j >> 3) & 3, jjd = j & 7;
#pragma unroll
                    for (int r = 0; r < 4; ++r) {
                        const int m = mt * 16 + quad * 4 + r;  // C layout: row = quad*4+reg
                        const int sg = c * 8 + m / 6;
                        const int e1 = ((ktd * 64 + (sg | (qd << 4))) * 8 + jjd);
                        const ushort_t bm =
                            (v1hi[e1] != 0) ? f2bf(cc[mt][n][r]) : (ushort_t)0;
                        A2[((mt * 8 + ktd) * 64 + ((m & 15) | (qd << 4))) * 8 + jjd] = bm;
                    }
                }
            }
            __syncthreads();

            // phase D: J = Bm @ w1e (M=48 N=16 K=256); waves 0-2
            f32x4 dc = {0, 0, 0, 0};
            if (wave < 3) {
#pragma unroll
                for (int kt = 0; kt < 8; ++kt) {
                    bf16x8 a = *(const bf16x8*)&A2[((wave * 8 + kt) * 64 + lane) * 8];
                    bf16x8 b = *(const bf16x8*)&g_w1e[(kt * 64 + lane) * 8];
                    dc = __builtin_amdgcn_mfma_f32_16x16x32_bf16(a, b, dc, 0, 0, 0);
                }
            }
            __syncthreads();  // A2 reads done; region now reusable for Jsh/ydsh

            if (wave < 3) {
                if (l15 < 8) {
#pragma unroll
                    for (int r = 0; r < 4; ++r) {
                        const int m = wave * 16 + quad * 4 + r;
                        Jsh[m * 8 + l15] = dc[r];
                    }
                }
            } else {  // ydot from the diag of the extra tile (col = global sample idx)
#pragma unroll
                for (int mt = 0; mt < 3; ++mt) {
#pragma unroll
                    for (int r = 0; r < 4; ++r) {
                        const int m = mt * 16 + quad * 4 + r;
                        const int sl = m / 6, i = m - sl * 6;
                        if (l15 == c * 8 + sl) ydsh[m] = cy[mt][r] + b3[i];
                    }
                }
            }
            __syncthreads();

            // coalesced output for this chunk's 8 samples
            {
                const int s0c = s0 + c * 8;
                const long base6 = (long)s0c * 6;
                {
                    const int u = tid;  // dy dwords 0..255
                    const int s = u / 36, rem = u - s * 36, ii = rem / 6, jy = rem - ii * 6;
                    out[OFF_DY + (long)s0c * 36 + u] = Jsh[(s * 6 + ii) * 8 + jy];
                }
                if (tid < 32) {  // dy dwords 256..287
                    const int u = 256 + tid;
                    const int s = u / 36, rem = u - s * 36, ii = rem / 6, jy = rem - ii * 6;
                    out[OFF_DY + (long)s0c * 36 + u] = Jsh[(s * 6 + ii) * 8 + jy];
                }
                if (tid < 48) out[OFF_YDOT + base6 + tid] = ydsh[tid];
                const int t2 = tid - 64;
                if (t2 >= 0 && t2 < 48) out[OFF_DE + base6 + t2] = Jsh[t2 * 8 + 6];
                const int t3 = tid - 128;
                if (t3 >= 0 && t3 < 48) out[OFF_DT + base6 + t3] = Jsh[t3 * 8 + 7];
            }
        }
        __syncthreads();
    }
}

extern "C" void kernel_launch(void* const* d_in, const int* in_sizes, int n_in,
                              void* d_out, int out_size, void* d_ws, size_t ws_size,
                              hipStream_t stream) {
    // setup_inputs order: t(0,unused), y(1), erate(2), T(3), w1(4), w2(5), w3(6), b1(7), b2(8), b3(9)
    const float* y     = (const float*)d_in[1];
    const float* erate = (const float*)d_in[2];
    const float* Tin   = (const float*)d_in[3];
    const float* w1    = (const float*)d_in[4];
    const float* w2    = (const float*)d_in[5];
    const float* w3    = (const float*)d_in[6];
    const float* b1    = (const float*)d_in[7];
    const float* b2    = (const float*)d_in[8];
    const float* b3    = (const float*)d_in[9];
    float* out = (float*)d_out;

    prep_kernel<<<dim3(64), dim3(256), 0, stream>>>(w1, w2, w3);
    fused_kernel<<<dim3(NG16), dim3(256), 0, stream>>>(
        y, erate, Tin, w1, b1, b2, b3, out);
}

// Round 5
// 410.023 us; speedup vs baseline: 2.6853x; 1.2466x over previous
//
#include <hip/hip_runtime.h>
#include <hip/hip_bf16.h>

// NeuralInelasticModel fused fwd + Jacobian, MFMA bf16, SB=16 samples/block.
// 65536 samples, NS=6, NI=8, H=256.
// out = [ydot(65536*6) | dy(65536*36) | de(65536*6) | dT(65536*6)]
// z2 (sign feeds m2 mask) via 3-term bf16 split (6 MFMA products) -> fp32-chain accuracy.
// m1 mask lives in per-thread registers (16-bit), moved cross-lane via __shfl.

typedef unsigned short ushort_t;
typedef __attribute__((ext_vector_type(8))) short bf16x8;   // 8 bf16 = 4 VGPRs
typedef __attribute__((ext_vector_type(4))) float f32x4;

#define NSAMP (64 * 1024)
#define NG16 (NSAMP / 16)
#define OFF_YDOT 0
#define OFF_DY (NSAMP * 6)
#define OFF_DE (OFF_DY + NSAMP * 36)
#define OFF_DT (OFF_DE + NSAMP * 6)

// Weights repacked into MFMA B-fragment order:
// frag elem idx = ((nt*8 + kt)*64 + lane)*8 + jj,
// value = B[k = kt*32 + (lane>>4)*8 + jj][n = nt*16 + (lane&15)]
__device__ __align__(16) ushort_t g_w2T_hi[65536];   // z2 GEMM: B[k=j][n=h] = w2[h][j]
__device__ __align__(16) ushort_t g_w2T_mid[65536];
__device__ __align__(16) ushort_t g_w2T_lo[65536];
__device__ __align__(16) ushort_t g_w2B[65536];      // B GEMM:  B[k=h][n=j] = w2[h][j]
__device__ __align__(16) ushort_t g_w1e[4096];       // J GEMM:  B[k=j][n=kout] = w1[j][kout] (kout<8 else 0)
__device__ __align__(16) ushort_t g_w3b[1536];       // w3 bf16 row-major [6][256]

static __device__ __forceinline__ ushort_t f2bf(float f) {
    union { __hip_bfloat16 b; ushort_t u; } c;
    c.b = __float2bfloat16(f);
    return c.u;
}
static __device__ __forceinline__ float bf2f(ushort_t u) {
    union { ushort_t u; __hip_bfloat16 b; } c;
    c.u = u;
    return __bfloat162float(c.b);
}

__global__ void prep_kernel(const float* __restrict__ w1, const float* __restrict__ w2,
                            const float* __restrict__ w3) {
    const int gtid = blockIdx.x * blockDim.x + threadIdx.x;
    const int stride = gridDim.x * blockDim.x;
    for (int idx = gtid; idx < 65536; idx += stride) {
        const int nt = idx >> 12, kt = (idx >> 9) & 7, L = (idx >> 3) & 63, jj = idx & 7;
        const int n = nt * 16 + (L & 15);
        const int k = kt * 32 + ((L >> 4) & 3) * 8 + jj;
        const float vT = w2[n * 256 + k];          // w2T: B[k=j][n=h]
        const ushort_t hi = f2bf(vT);
        const float r1 = vT - bf2f(hi);
        const ushort_t mid = f2bf(r1);
        g_w2T_hi[idx]  = hi;
        g_w2T_mid[idx] = mid;
        g_w2T_lo[idx]  = f2bf(r1 - bf2f(mid));
        g_w2B[idx] = f2bf(w2[k * 256 + n]);        // w2B: B[k=h][n=j]
    }
    for (int idx = gtid; idx < 4096; idx += stride) {
        const int kt = idx >> 9, L = (idx >> 3) & 63, jj = idx & 7;
        const int kout = L & 15;
        const int j = kt * 32 + ((L >> 4) & 3) * 8 + jj;
        g_w1e[idx] = (kout < 8) ? f2bf(w1[j * 8 + kout]) : (ushort_t)0;
    }
    for (int idx = gtid; idx < 1536; idx += stride) g_w3b[idx] = f2bf(w3[idx]);
}

// LDS layout (40960 B total -> 4 blocks/CU):
//   0      v1hi: A-frag [8 kt][64 lane][8 jj] bf16 (8192). Dead after phase B
//            (m1 mask is in registers now). Post-B aliases:
//            Jsh [48][8] f32 @0 (1536), ydsh[48] f32 @1536 (192)
//   8192   A2:  A-frag [3 mt][8 kt][64][8] bf16 (24576). Pre-B aliases:
//            v1mid @8192 (8192), v1lo @16384 (8192), xs [16][8] f32 @24576 (512)
//   32768  v2B: B-frag [8 kt][64][8] bf16 (8192); n-dim = sample 0..15; doubles as m2 mask.
#define SMEM_BYTES 40960

__global__ __launch_bounds__(256, 4) void fused_kernel(
    const float* __restrict__ y, const float* __restrict__ erate,
    const float* __restrict__ Tin, const float* __restrict__ w1,
    const float* __restrict__ b1, const float* __restrict__ b2,
    const float* __restrict__ b3, float* __restrict__ out)
{
    __shared__ __align__(16) char smem[SMEM_BYTES];
    ushort_t* v1hi  = (ushort_t*)(smem + 0);
    float*    Jsh   = (float*)(smem + 0);      // alias: v1hi dead after phase B
    float*    ydsh  = (float*)(smem + 1536);
    ushort_t* v1mid = (ushort_t*)(smem + 8192);
    ushort_t* v1lo  = (ushort_t*)(smem + 16384);
    ushort_t* A2    = (ushort_t*)(smem + 8192);
    float*    xs    = (float*)(smem + 24576);
    ushort_t* v2B   = (ushort_t*)(smem + 32768);

    const int tid  = threadIdx.x;
    const int lane = tid & 63;
    const int wave = tid >> 6;
    const int l15  = lane & 15;
    const int quad = lane >> 4;

    // per-thread weight regs for z1 (thread tid == hidden unit j)
    float w1r[8];
#pragma unroll
    for (int k = 0; k < 8; ++k) w1r[k] = w1[tid * 8 + k];
    const float b1r = b1[tid];
    float b2v[4];
#pragma unroll
    for (int n = 0; n < 4; ++n) b2v[n] = b2[(wave * 4 + n) * 16 + l15];

    const int g = blockIdx.x;
    const int s0 = g * 16;

    // ---- stage x for 16 samples ----
    if (tid < 128) {
        const int s = tid >> 3, k = tid & 7;
        float v;
        if (k < 6)       v = y[(s0 + s) * 6 + k];
        else if (k == 6) v = erate[s0 + s];
        else             v = Tin[s0 + s];
        xs[s * 8 + k] = v;
    }
    __syncthreads();

    // ---- z1 (exact fp32) + 3-way bf16 split of v1 (A-frag layout) + register m1 mask ----
    unsigned int m1self = 0;  // bit s = (z1[s][tid] > 0)
    {
        const int ktw = tid >> 5, qd = (tid >> 3) & 3, jj = tid & 7;
#pragma unroll 1
        for (int s = 0; s < 16; ++s) {
            float z = b1r;
#pragma unroll
            for (int k = 0; k < 8; ++k) z = fmaf(w1r[k], xs[s * 8 + k], z);
            const float v = fmaxf(z, 0.0f);
            m1self |= (v > 0.0f ? 1u : 0u) << s;
            const ushort_t hi = f2bf(v);
            const float r1 = v - bf2f(hi);
            const ushort_t mid = f2bf(r1);
            const int e = ((ktw * 64 + (s | (qd << 4))) * 8 + jj);
            v1hi[e]  = hi;
            v1mid[e] = mid;
            v1lo[e]  = f2bf(r1 - bf2f(mid));
        }
    }
    __syncthreads();

    // ---- phase B: z2 = v1 @ w2^T, 3-way split (6 MFMAs), M=16(s) N=256(h) K=256(j) ----
    {
        f32x4 cz[4];
#pragma unroll
        for (int n = 0; n < 4; ++n) cz[n] = (f32x4){0, 0, 0, 0};
#pragma unroll 2
        for (int kt = 0; kt < 8; ++kt) {
            const int aoff = (kt * 64 + lane) * 8;
            bf16x8 ahi = *(const bf16x8*)&v1hi[aoff];
            bf16x8 ami = *(const bf16x8*)&v1mid[aoff];
            bf16x8 alo = *(const bf16x8*)&v1lo[aoff];
#pragma unroll
            for (int n = 0; n < 4; ++n) {
                const int bidx = (((wave * 4 + n) * 8 + kt) * 64 + lane) * 8;
                bf16x8 bh = *(const bf16x8*)&g_w2T_hi[bidx];
                bf16x8 bm = *(const bf16x8*)&g_w2T_mid[bidx];
                bf16x8 bl = *(const bf16x8*)&g_w2T_lo[bidx];
                cz[n] = __builtin_amdgcn_mfma_f32_16x16x32_bf16(alo, bh, cz[n], 0, 0, 0);
                cz[n] = __builtin_amdgcn_mfma_f32_16x16x32_bf16(ami, bm, cz[n], 0, 0, 0);
                cz[n] = __builtin_amdgcn_mfma_f32_16x16x32_bf16(ahi, bl, cz[n], 0, 0, 0);
                cz[n] = __builtin_amdgcn_mfma_f32_16x16x32_bf16(ami, bh, cz[n], 0, 0, 0);
                cz[n] = __builtin_amdgcn_mfma_f32_16x16x32_bf16(ahi, bm, cz[n], 0, 0, 0);
                cz[n] = __builtin_amdgcn_mfma_f32_16x16x32_bf16(ahi, bh, cz[n], 0, 0, 0);
            }
        }
        // epilogue: v2 = relu(z2 + b2) -> v2B (B-frag layout, n=sample; doubles as m2)
#pragma unroll
        for (int n = 0; n < 4; ++n) {
            const int h = (wave * 4 + n) * 16 + l15;
            const int ktd = h >> 5, qd = (h >> 3) & 3, jj = h & 7;
#pragma unroll
            for (int r = 0; r < 4; ++r) {
                const int s = quad * 4 + r;  // C layout: row = quad*4 + reg
                const float v2 = fmaxf(cz[n][r] + b2v[n], 0.0f);
                v2B[(ktd * 64 + (s | (qd << 4))) * 8 + jj] = f2bf(v2);
            }
        }
    }
    __syncthreads();

    // ---- chunks of 8 samples: phases C (B=A2@w2), Bm, D (J=Bm@w1e), epilogue ----
#pragma unroll 1
    for (int c = 0; c < 2; ++c) {
        // build A2[m = sl*6+i][h] = m2[sg][h] ? w3[i][h] : 0, A-frag layout
        // (no barrier needed before this: A2 region reads of prev chunk were
        //  barrier-protected after phase D; v2B is stable)
        if (tid < 192) {
            const int mt = tid >> 6;
            const int m = mt * 16 + l15;
            const int sl = m / 6, i = m - sl * 6;
            const int sg = c * 8 + sl;
#pragma unroll 1
            for (int kt = 0; kt < 8; ++kt) {
                bf16x8 vv = *(const bf16x8*)&v2B[(kt * 64 + (sg | (quad << 4))) * 8];
                bf16x8 wv = *(const bf16x8*)&g_w3b[i * 256 + kt * 32 + quad * 8];
                bf16x8 o;
#pragma unroll
                for (int e = 0; e < 8; ++e)
                    o[e] = ((ushort_t)vv[e] != 0) ? wv[e] : (short)0;
                *(bf16x8*)&A2[((mt * 8 + kt) * 64 + lane) * 8] = o;
            }
        }
        __syncthreads();

        // phase C: B = A2 @ w2 (M=48 N=256 K=256); wave 3 also does ydot tile
        f32x4 cc[3][4], cy[3];
#pragma unroll
        for (int mt = 0; mt < 3; ++mt) {
#pragma unroll
            for (int n = 0; n < 4; ++n) cc[mt][n] = (f32x4){0, 0, 0, 0};
            cy[mt] = (f32x4){0, 0, 0, 0};
        }
#pragma unroll 2
        for (int kt = 0; kt < 8; ++kt) {
            bf16x8 a[3];
#pragma unroll
            for (int mt = 0; mt < 3; ++mt)
                a[mt] = *(const bf16x8*)&A2[((mt * 8 + kt) * 64 + lane) * 8];
#pragma unroll
            for (int n = 0; n < 4; ++n) {
                bf16x8 b = *(const bf16x8*)&g_w2B[(((wave * 4 + n) * 8 + kt) * 64 + lane) * 8];
#pragma unroll
                for (int mt = 0; mt < 3; ++mt)
                    cc[mt][n] = __builtin_amdgcn_mfma_f32_16x16x32_bf16(a[mt], b, cc[mt][n], 0, 0, 0);
            }
            if (wave == 3) {
                bf16x8 bv = *(const bf16x8*)&v2B[(kt * 64 + lane) * 8];
#pragma unroll
                for (int mt = 0; mt < 3; ++mt)
                    cy[mt] = __builtin_amdgcn_mfma_f32_16x16x32_bf16(a[mt], bv, cy[mt], 0, 0, 0);
            }
        }
        __syncthreads();  // all A2 reads complete before Bm overwrites

        // epilogue: Bm = (B .* m1) -> bf16, back into A2 (A-frag layout).
        // m1 mask via in-wave shuffle: column j's mask is held by lane n*16+l15.
#pragma unroll
        for (int n = 0; n < 4; ++n) {
            const unsigned int mcol = (unsigned int)__shfl((int)m1self, n * 16 + l15, 64);
            const int j = (wave * 4 + n) * 16 + l15;  // C layout: col = lane&15
            const int ktd = j >> 5, qd = (j >> 3) & 3, jjd = j & 7;
#pragma unroll
            for (int mt = 0; mt < 3; ++mt) {
#pragma unroll
                for (int r = 0; r < 4; ++r) {
                    const int m = mt * 16 + quad * 4 + r;  // C layout: row = quad*4+reg
                    const int sg = c * 8 + m / 6;
                    const ushort_t bm =
                        ((mcol >> sg) & 1u) ? f2bf(cc[mt][n][r]) : (ushort_t)0;
                    A2[((mt * 8 + ktd) * 64 + ((m & 15) | (qd << 4))) * 8 + jjd] = bm;
                }
            }
        }
        __syncthreads();

        // phase D: J = Bm @ w1e (M=48 N=16 K=256); waves 0-2. Wave 3 writes ydot.
        if (wave < 3) {
            f32x4 dc = {0, 0, 0, 0};
#pragma unroll 1
            for (int kt = 0; kt < 8; ++kt) {
                bf16x8 a = *(const bf16x8*)&A2[((wave * 8 + kt) * 64 + lane) * 8];
                bf16x8 b = *(const bf16x8*)&g_w1e[(kt * 64 + lane) * 8];
                dc = __builtin_amdgcn_mfma_f32_16x16x32_bf16(a, b, dc, 0, 0, 0);
            }
            if (l15 < 8) {
#pragma unroll
                for (int r = 0; r < 4; ++r) {
                    const int m = wave * 16 + quad * 4 + r;
                    Jsh[m * 8 + l15] = dc[r];
                }
            }
        } else {  // ydot from the diag of the extra tile (col = global sample idx)
#pragma unroll
            for (int mt = 0; mt < 3; ++mt) {
#pragma unroll
                for (int r = 0; r < 4; ++r) {
                    const int m = mt * 16 + quad * 4 + r;
                    const int sl = m / 6, i = m - sl * 6;
                    if (l15 == c * 8 + sl) ydsh[m] = cy[mt][r] + b3[i];
                }
            }
        }
        __syncthreads();

        // coalesced output for this chunk's 8 samples
        {
            const int s0c = s0 + c * 8;
            const long base6 = (long)s0c * 6;
            {
                const int u = tid;  // dy dwords 0..255
                const int s = u / 36, rem = u - s * 36, ii = rem / 6, jy = rem - ii * 6;
                out[OFF_DY + (long)s0c * 36 + u] = Jsh[(s * 6 + ii) * 8 + jy];
            }
            if (tid < 32) {  // dy dwords 256..287
                const int u = 256 + tid;
                const int s = u / 36, rem = u - s * 36, ii = rem / 6, jy = rem - ii * 6;
                out[OFF_DY + (long)s0c * 36 + u] = Jsh[(s * 6 + ii) * 8 + jy];
            }
            if (tid < 48) out[OFF_YDOT + base6 + tid] = ydsh[tid];
            const int t2 = tid - 64;
            if (t2 >= 0 && t2 < 48) out[OFF_DE + base6 + t2] = Jsh[t2 * 8 + 6];
            const int t3 = tid - 128;
            if (t3 >= 0 && t3 < 48) out[OFF_DT + base6 + t3] = Jsh[t3 * 8 + 7];
        }
        // no barrier here: next chunk's A2 build touches neither Jsh (v1hi region)
        // nor any region read by the staging stores; phase-D reads of A2 were
        // already barrier-protected.
    }
}

extern "C" void kernel_launch(void* const* d_in, const int* in_sizes, int n_in,
                              void* d_out, int out_size, void* d_ws, size_t ws_size,
                              hipStream_t stream) {
    // setup_inputs order: t(0,unused), y(1), erate(2), T(3), w1(4), w2(5), w3(6), b1(7), b2(8), b3(9)
    const float* y     = (const float*)d_in[1];
    const float* erate = (const float*)d_in[2];
    const float* Tin   = (const float*)d_in[3];
    const float* w1    = (const float*)d_in[4];
    const float* w2    = (const float*)d_in[5];
    const float* w3    = (const float*)d_in[6];
    const float* b1    = (const float*)d_in[7];
    const float* b2    = (const float*)d_in[8];
    const float* b3    = (const float*)d_in[9];
    float* out = (float*)d_out;

    prep_kernel<<<dim3(64), dim3(256), 0, stream>>>(w1, w2, w3);
    fused_kernel<<<dim3(NG16), dim3(256), 0, stream>>>(
        y, erate, Tin, w1, b1, b2, b3, out);
}